// Round 3
// baseline (1142.664 us; speedup 1.0000x reference)
//
#include <hip/hip_runtime.h>
#include <math.h>

#define BB 2
#define NN 512
#define CSZ 384
#define HH 12
#define CC 16
#define PP 8
#define PVV 8
#define KG 16
#define GG 64
#define NCOL 912
#define NODES (BB*NN)

// ---------------- K0: weight prep ----------------
__global__ void k0_prep(const float* __restrict__ Wq, const float* __restrict__ Wkv,
                        const float* __restrict__ Wpq, const float* __restrict__ Wpv,
                        const float* __restrict__ Wkvp,
                        const float* __restrict__ bq, const float* __restrict__ bkv,
                        const float* __restrict__ bpq, const float* __restrict__ bpv,
                        const float* __restrict__ bkvp,
                        const float* __restrict__ ln_g, const float* __restrict__ ln_b,
                        const float* __restrict__ W1, const float* __restrict__ hwin,
                        float* __restrict__ Wbig, float* __restrict__ biasbig,
                        float* __restrict__ P2big, float* __restrict__ W1T,
                        float* __restrict__ hw)
{
  int idx = blockIdx.x*blockDim.x + threadIdx.x;
  int stride = gridDim.x*blockDim.x;
  for (int t = idx; t < CSZ*NCOL; t += stride) {
    int f = t / NCOL, c = t % NCOL;
    float w;
    if (c < 192)      w = Wq[f*192 + c];
    else if (c < 576) w = Wkv[f*384 + (c-192)];
    else if (c < 600) w = ln_g[f]*Wpq[f*24 + (c-576)];
    else if (c < 624) w = ln_g[f]*Wpv[f*24 + (c-600)];
    else              w = Wkvp[f*288 + (c-624)];
    Wbig[t] = w;
  }
  for (int t = idx; t < 64*64; t += stride) {
    int ho = t >> 6, kk = t & 63;
    W1T[t] = W1[kk*64 + ho];
  }
  for (int c = idx; c < NCOL; c += stride) {
    float bb, p2 = 0.f;
    if (c < 192)      bb = bq[c];
    else if (c < 576) bb = bkv[c-192];
    else if (c < 624) {
      const float* W = (c < 600) ? (Wpq + (c-576)) : (Wpv + (c-600));
      float p1 = 0.f;
      for (int f = 0; f < CSZ; ++f) { p1 += ln_b[f]*W[f*24]; p2 += ln_g[f]*W[f*24]; }
      bb = ((c < 600) ? bpq[c-576] : bpv[c-600]) + p1;
    }
    else bb = bkvp[c-624];
    biasbig[c] = bb; P2big[c] = p2;
  }
  for (int h = idx; h < HH; h += stride) {
    float x = hwin[h];
    float sp = (x > 20.f) ? x : log1pf(expf(x));
    hw[h] = sp * sqrtf(1.0f/18.0f) * -0.5f;   // AFS=4, AFS*4.5=18
  }
}

// ---------------- K0b: layernorm stats ----------------
__global__ void k0b_stats(const float* __restrict__ s, float* __restrict__ mout,
                          float* __restrict__ rstdout)
{
  int node = blockIdx.x;
  int l = threadIdx.x;                 // 64 threads = 1 wave
  const float* row = s + node*CSZ;
  float sum = 0.f, sum2 = 0.f;
  for (int f = l; f < CSZ; f += 64) { float v = row[f]; sum += v; sum2 += v*v; }
  #pragma unroll
  for (int off = 1; off < 64; off <<= 1) { sum += __shfl_xor(sum, off); sum2 += __shfl_xor(sum2, off); }
  if (l == 0) {
    float m = sum / CSZ;
    float var = sum2 / CSZ - m*m;
    mout[node] = m;
    rstdout[node] = rsqrtf(var + 1e-5f);
  }
}

// ---------------- K1: fused node GEMM ----------------
__launch_bounds__(256)
__global__ void k1_gemm(const float* __restrict__ s, const float* __restrict__ Wbig,
                        const float* __restrict__ biasbig, const float* __restrict__ P2big,
                        const float* __restrict__ mrow, const float* __restrict__ rstd,
                        float* __restrict__ act)
{
  const int ROWS = 8;
  int row0 = blockIdx.x * ROWS;   // grid 128
  int t = threadIdx.x;            // 256
  float acc[4][ROWS];
  #pragma unroll
  for (int j = 0; j < 4; ++j)
    #pragma unroll
    for (int r = 0; r < ROWS; ++r) acc[j][r] = 0.f;

  int c3 = t + 768;
  #pragma unroll 4
  for (int f = 0; f < CSZ; ++f) {
    const float* wrow = Wbig + f*NCOL;
    float w0 = wrow[t], w1 = wrow[t+256], w2 = wrow[t+512];
    float w3 = (c3 < NCOL) ? wrow[c3] : 0.f;
    #pragma unroll
    for (int r = 0; r < ROWS; ++r) {
      float sv = s[(row0+r)*CSZ + f];     // uniform -> scalar load
      acc[0][r] = fmaf(sv, w0, acc[0][r]);
      acc[1][r] = fmaf(sv, w1, acc[1][r]);
      acc[2][r] = fmaf(sv, w2, acc[2][r]);
      acc[3][r] = fmaf(sv, w3, acc[3][r]);
    }
  }
  #pragma unroll
  for (int j = 0; j < 4; ++j) {
    int c = t + j*256;
    if (c < NCOL) {
      float bb = biasbig[c], p2v = P2big[c];
      bool lncol = (c >= 576 && c < 624);
      #pragma unroll
      for (int r = 0; r < ROWS; ++r) {
        int node = row0 + r;
        float v;
        if (lncol) { float rs = rstd[node]; v = acc[j][r]*rs + bb - mrow[node]*rs*p2v; }
        else       v = acc[j][r] + bb;
        act[node*NCOL + c] = v;
      }
    }
  }
}

// ---------------- K1b: v transpose + vg compute ----------------
__global__ void k1b_post(const float* __restrict__ act, const float* __restrict__ rot,
                         const float* __restrict__ trans,
                         float* __restrict__ vT, float* __restrict__ vgT)
{
  int idx = blockIdx.x*blockDim.x + threadIdx.x;
  const int NT1 = BB*HH*CC*NN;       // 196608
  const int NT2 = BB*HH*PVV*3*NN;    // 294912
  if (idx < NT1) {
    int n = idx & (NN-1); int rest = idx >> 9;
    int c = rest & 15; rest >>= 4;
    int h = rest % HH; int b = rest / HH;
    int node = b*NN + n;
    vT[idx] = act[node*NCOL + 192 + h*32 + 16 + c];
  } else if (idx < NT1 + NT2) {
    int j = idx - NT1;
    int n = j & (NN-1); int rest = j >> 9;
    int p3 = rest % 24; rest /= 24;
    int h = rest % HH; int b = rest / HH;
    int node = b*NN + n;
    int p = p3 / 3, x = p3 % 3;
    int hp = h*PVV + p;
    const float* kp = act + node*NCOL + 624 + hp*3;
    const float* R = rot + node*9;
    vgT[j] = R[x*3+0]*kp[0] + R[x*3+1]*kp[1] + R[x*3+2]*kp[2] + trans[node*3+x]*0.1f;
  }
}

// ---------------- K2 helper: geometry + vlen for one j ----------------
__device__ __forceinline__ void k2_vlen(const float* __restrict__ act,
                                        const float* __restrict__ rot,
                                        const float* __restrict__ trans,
                                        const float* __restrict__ Wvl,
                                        const float* s_qvec,
                                        const float ri[9], float ti0, float ti1, float ti2,
                                        int jnode, float vlen[8], float& pd)
{
  const float* actj = act + (size_t)jnode*NCOL;
  float rj[9];
  #pragma unroll
  for (int q = 0; q < 9; ++q) rj[q] = rot[(size_t)jnode*9 + q];
  float tj0 = trans[jnode*3], tj1 = trans[jnode*3+1], tj2 = trans[jnode*3+2];

  float Rr[9];
  #pragma unroll
  for (int x = 0; x < 3; ++x)
    #pragma unroll
    for (int z = 0; z < 3; ++z)
      Rr[x*3+z] = ri[x]*rj[z] + ri[3+x]*rj[3+z] + ri[6+x]*rj[6+z];

  float d0 = tj0-ti0, d1 = tj1-ti1, d2 = tj2-ti2;
  pd = 0.01f * (d0*d0 + d1*d1 + d2*d2);
  float tr[3];
  #pragma unroll
  for (int x = 0; x < 3; ++x) tr[x] = ri[x]*d0 + ri[3+x]*d1 + ri[6+x]*d2;

  float vpl[24];
  {
    const float4* v4 = (const float4*)(actj + 600);
    #pragma unroll
    for (int q = 0; q < 6; ++q) {
      float4 x4 = v4[q];
      vpl[q*4+0] = x4.x; vpl[q*4+1] = x4.y; vpl[q*4+2] = x4.z; vpl[q*4+3] = x4.w;
    }
  }
  #pragma unroll
  for (int p = 0; p < PP; ++p) {
    float x0 = vpl[p*3], x1 = vpl[p*3+1], x2 = vpl[p*3+2];
    float l0 = fmaf(Rr[0], x0, fmaf(Rr[1], x1, fmaf(Rr[2], x2, tr[0])));
    float l1 = fmaf(Rr[3], x0, fmaf(Rr[4], x1, fmaf(Rr[5], x2, tr[1])));
    float l2 = fmaf(Rr[6], x0, fmaf(Rr[7], x1, fmaf(Rr[8], x2, tr[2])));
    vpl[p*3] = l0; vpl[p*3+1] = l1; vpl[p*3+2] = l2;
  }
  #pragma unroll
  for (int o = 0; o < 8; ++o) {
    float vx = vpl[o*3+0] + s_qvec[o*3+0];
    float vy = vpl[o*3+1] + s_qvec[o*3+1];
    float vz = vpl[o*3+2] + s_qvec[o*3+2];
    #pragma unroll
    for (int p = 0; p < PP; ++p) {
      float w = Wvl[o*16+p];          // uniform -> scalar (256B, sL1-resident)
      vx = fmaf(w, vpl[p*3+0], vx);
      vy = fmaf(w, vpl[p*3+1], vy);
      vz = fmaf(w, vpl[p*3+2], vz);
    }
    vlen[o] = sqrtf(vx*vx + vy*vy + vz*vz + 1e-8f);
  }
}

// ---------------- K2: fused pair kernel, NJ=2 + VMEM weights ----------------
// grid 1024 = (b,i); 256 threads; thread t handles j=t and j=t+256.
// One weight-row fetch now feeds 128 FMAs (r0: 64, r1: 32 -> both stalled).
// Weights go through VMEM vector loads (opaque-zero defeats scalar promotion):
// ~63 outstanding loads/wave + vL1-resident 48KB working set, instead of the
// serialized scalar-pipe stream (r0/r1) or the LDS broadcast pipe (r2).
__launch_bounds__(256)
__global__ void k2_pair(const float* __restrict__ act, const float* __restrict__ rot,
                        const float* __restrict__ trans, const float* __restrict__ mask,
                        const float* __restrict__ Wvl, const float* __restrict__ gm_in,
                        const float* __restrict__ gs_in,
                        const float* __restrict__ Wg, const float* __restrict__ bg,
                        const float* __restrict__ W1T, const float* __restrict__ b1,
                        const float* __restrict__ W2, const float* __restrict__ b2,
                        const float* __restrict__ hw,
                        float* __restrict__ gout, float* __restrict__ apre)
{
  __shared__ float s_qvec[PP*3];
  __shared__ float s_gm[KG], s_gis[KG];
  __shared__ float s_hw[HH];

  int bi = blockIdx.x;              // b*512 + i
  int b = bi >> 9, i = bi & (NN-1);
  int t = threadIdx.x;              // 256
  const float* acti = act + (size_t)bi*NCOL;

  // opaque zero: forces weight loads onto the VMEM (vector) path
  int zz; asm volatile("v_mov_b32 %0, 0" : "=v"(zz));

  if (t < 24) {
    int o = t / 3, c = t % 3;
    float sum = 0.f;
    #pragma unroll
    for (int p = 0; p < PP; ++p) sum += Wvl[o*16 + 8 + p] * acti[576 + p*3 + c];
    s_qvec[t] = sum;
  } else if (t >= 32 && t < 48) {
    int k = t - 32; s_gm[k] = gm_in[k]; s_gis[k] = 1.f / gs_in[k];
  } else if (t >= 64 && t < 76) {
    s_hw[t-64] = hw[t-64];
  }
  __syncthreads();

  const float* Ri = rot + (size_t)bi*9;   // block-uniform -> scalar
  float ri[9];
  #pragma unroll
  for (int q = 0; q < 9; ++q) ri[q] = Ri[q];
  float ti0 = trans[bi*3], ti1 = trans[bi*3+1], ti2 = trans[bi*3+2];
  float mi = mask[bi];

  int j0 = t, j1 = t + 256;
  int jn0 = b*NN + j0, jn1 = b*NN + j1;

  float vlen0[8], vlen1[8];
  float pd0, pd1;
  k2_vlen(act, rot, trans, Wvl, s_qvec, ri, ti0, ti1, ti2, jn0, vlen0, pd0);
  k2_vlen(act, rot, trans, Wvl, s_qvec, ri, ti0, ti1, ti2, jn1, vlen1, pd1);

  // ---- g = gauss @ Wg + bg  (one row fetch -> 128 FMAs) ----
  float acc0[64], acc1[64];
  #pragma unroll
  for (int q = 0; q < 64; ++q) { float bb = bg[q]; acc0[q] = bb; acc1[q] = bb; }

  #pragma unroll 1
  for (int o = 0; o < 8; ++o) {
    float gv0[KG], gv1[KG];
    #pragma unroll
    for (int k = 0; k < KG; ++k) {
      float t0 = (vlen0[o] - s_gm[k]) * s_gis[k];
      float t1 = (vlen1[o] - s_gm[k]) * s_gis[k];
      gv0[k] = __expf(-0.5f * t0 * t0);
      gv1[k] = __expf(-0.5f * t1 * t1);
    }
    const float* wbase = Wg + o*KG*64 + zz;   // VGPR base -> VMEM loads
    #pragma unroll 2
    for (int k = 0; k < KG; ++k) {
      float gk0 = gv0[k], gk1 = gv1[k];
      const float4* wr4 = (const float4*)(wbase + k*64);
      #pragma unroll
      for (int q = 0; q < 16; ++q) {
        float4 w4 = wr4[q];
        acc0[4*q+0] = fmaf(gk0, w4.x, acc0[4*q+0]);
        acc0[4*q+1] = fmaf(gk0, w4.y, acc0[4*q+1]);
        acc0[4*q+2] = fmaf(gk0, w4.z, acc0[4*q+2]);
        acc0[4*q+3] = fmaf(gk0, w4.w, acc0[4*q+3]);
        acc1[4*q+0] = fmaf(gk1, w4.x, acc1[4*q+0]);
        acc1[4*q+1] = fmaf(gk1, w4.y, acc1[4*q+1]);
        acc1[4*q+2] = fmaf(gk1, w4.z, acc1[4*q+2]);
        acc1[4*q+3] = fmaf(gk1, w4.w, acc1[4*q+3]);
      }
    }
  }

  // write g (output 1)
  {
    float4* g0 = (float4*)(gout + ((size_t)bi*NN + j0)*64);
    float4* g1 = (float4*)(gout + ((size_t)bi*NN + j1)*64);
    #pragma unroll
    for (int q = 0; q < 16; ++q) {
      g0[q] = make_float4(acc0[4*q], acc0[4*q+1], acc0[4*q+2], acc0[4*q+3]);
      g1[q] = make_float4(acc1[4*q], acc1[4*q+1], acc1[4*q+2], acc1[4*q+3]);
    }
  }

  // ---- vfn = relu(g@W1+b1)@W2 + b2 ----
  float vf0[12], vf1[12];
  #pragma unroll
  for (int hh = 0; hh < 12; ++hh) { float bb = b2[hh]; vf0[hh] = bb; vf1[hh] = bb; }
  #pragma unroll 2
  for (int ho = 0; ho < 64; ++ho) {
    const float4* w1r = (const float4*)(W1T + ho*64 + zz);   // VMEM
    float bb1 = b1[ho];
    float a0 = bb1, b0 = 0.f, a1 = bb1, b1v = 0.f;
    #pragma unroll
    for (int q = 0; q < 8; ++q) {
      float4 wa = w1r[q];
      float4 wb = w1r[q+8];
      a0 = fmaf(acc0[4*q+0],  wa.x, a0); a0 = fmaf(acc0[4*q+1],  wa.y, a0);
      a0 = fmaf(acc0[4*q+2],  wa.z, a0); a0 = fmaf(acc0[4*q+3],  wa.w, a0);
      b0 = fmaf(acc0[32+4*q+0], wb.x, b0); b0 = fmaf(acc0[32+4*q+1], wb.y, b0);
      b0 = fmaf(acc0[32+4*q+2], wb.z, b0); b0 = fmaf(acc0[32+4*q+3], wb.w, b0);
      a1 = fmaf(acc1[4*q+0],  wa.x, a1); a1 = fmaf(acc1[4*q+1],  wa.y, a1);
      a1 = fmaf(acc1[4*q+2],  wa.z, a1); a1 = fmaf(acc1[4*q+3],  wa.w, a1);
      b1v = fmaf(acc1[32+4*q+0], wb.x, b1v); b1v = fmaf(acc1[32+4*q+1], wb.y, b1v);
      b1v = fmaf(acc1[32+4*q+2], wb.z, b1v); b1v = fmaf(acc1[32+4*q+3], wb.w, b1v);
    }
    float hs0 = fmaxf(a0 + b0, 0.f);
    float hs1 = fmaxf(a1 + b1v, 0.f);
    const float4* w2r = (const float4*)(W2 + ho*12 + zz);    // VMEM (48B, aligned)
    float4 wx = w2r[0], wy = w2r[1], wz = w2r[2];
    vf0[0] = fmaf(hs0, wx.x, vf0[0]); vf0[1] = fmaf(hs0, wx.y, vf0[1]);
    vf0[2] = fmaf(hs0, wx.z, vf0[2]); vf0[3] = fmaf(hs0, wx.w, vf0[3]);
    vf0[4] = fmaf(hs0, wy.x, vf0[4]); vf0[5] = fmaf(hs0, wy.y, vf0[5]);
    vf0[6] = fmaf(hs0, wy.z, vf0[6]); vf0[7] = fmaf(hs0, wy.w, vf0[7]);
    vf0[8] = fmaf(hs0, wz.x, vf0[8]); vf0[9] = fmaf(hs0, wz.y, vf0[9]);
    vf0[10] = fmaf(hs0, wz.z, vf0[10]); vf0[11] = fmaf(hs0, wz.w, vf0[11]);
    vf1[0] = fmaf(hs1, wx.x, vf1[0]); vf1[1] = fmaf(hs1, wx.y, vf1[1]);
    vf1[2] = fmaf(hs1, wx.z, vf1[2]); vf1[3] = fmaf(hs1, wx.w, vf1[3]);
    vf1[4] = fmaf(hs1, wy.x, vf1[4]); vf1[5] = fmaf(hs1, wy.y, vf1[5]);
    vf1[6] = fmaf(hs1, wy.z, vf1[6]); vf1[7] = fmaf(hs1, wy.w, vf1[7]);
    vf1[8] = fmaf(hs1, wz.x, vf1[8]); vf1[9] = fmaf(hs1, wz.y, vf1[9]);
    vf1[10] = fmaf(hs1, wz.z, vf1[10]); vf1[11] = fmaf(hs1, wz.w, vf1[11]);
  }

  // ---- qk + combine + write, per j ----
  const float* actj0 = act + (size_t)jn0*NCOL;
  const float* actj1 = act + (size_t)jn1*NCOL;
  float mj0 = mask[jn0], mj1 = mask[jn1];
  float mt0 = 100000.f * (mi*mj0 - 1.f);
  float mt1 = 100000.f * (mi*mj1 - 1.f);
  #pragma unroll
  for (int h = 0; h < 12; ++h) {
    const float4* k40 = (const float4*)(actj0 + 192 + h*32);
    const float4* k41 = (const float4*)(actj1 + 192 + h*32);
    float q0 = 0.f, q1 = 0.f;
    #pragma unroll
    for (int q = 0; q < 4; ++q) {
      float4 kv0 = k40[q];
      float4 kv1 = k41[q];
      const float* qp = acti + h*16 + q*4;   // uniform -> scalar
      q0 = fmaf(qp[0], kv0.x, q0); q0 = fmaf(qp[1], kv0.y, q0);
      q0 = fmaf(qp[2], kv0.z, q0); q0 = fmaf(qp[3], kv0.w, q0);
      q1 = fmaf(qp[0], kv1.x, q1); q1 = fmaf(qp[1], kv1.y, q1);
      q1 = fmaf(qp[2], kv1.z, q1); q1 = fmaf(qp[3], kv1.w, q1);
    }
    float* arow = apre + (((size_t)b*HH + h)*NN + i)*NN;
    arow[j0] = q0*0.125f + vf0[h]*0.5f + pd0*s_hw[h] + mt0;
    arow[j1] = q1*0.125f + vf1[h]*0.5f + pd1*s_hw[h] + mt1;
  }
}

// ---------------- K3: softmax + attend ----------------
__launch_bounds__(256)
__global__ void k3_attend(const float* __restrict__ apre, const float* __restrict__ vT,
                          const float* __restrict__ vgT,
                          float* __restrict__ oout, float* __restrict__ optout)
{
  __shared__ float a4t[4][NN];     // transposed: conflict-free b32 reads
  int blk = blockIdx.x;            // B*H*(N/4)
  int ic = blk & 127; int rest = blk >> 7;
  int h = rest % HH; int b = rest / HH;
  int i0 = ic * 4;
  int t = threadIdx.x; int w = t >> 6; int l = t & 63;

  { // phase 1: wave w -> row i0+w
    int i = i0 + w;
    const float* row = apre + (((size_t)b*HH + h)*NN + i)*NN;
    float vals[8];
    float m = -1e30f;
    #pragma unroll
    for (int s8 = 0; s8 < 8; ++s8) { vals[s8] = row[l + 64*s8]; m = fmaxf(m, vals[s8]); }
    #pragma unroll
    for (int off = 1; off < 64; off <<= 1) m = fmaxf(m, __shfl_xor(m, off));
    float sum = 0.f;
    #pragma unroll
    for (int s8 = 0; s8 < 8; ++s8) { vals[s8] = __expf(vals[s8] - m); sum += vals[s8]; }
    #pragma unroll
    for (int off = 1; off < 64; off <<= 1) sum += __shfl_xor(sum, off);
    float inv = 1.f / sum;
    #pragma unroll
    for (int s8 = 0; s8 < 8; ++s8) a4t[w][l + 64*s8] = vals[s8] * inv;
  }
  __syncthreads();

  const float* vbase = vT + ((size_t)(b*HH + h)*CC)*NN;
  const float* gbase = vgT + ((size_t)(b*HH + h)*24)*NN;
  #pragma unroll 1
  for (int pass = 0; pass < 5; ++pass) {
    int c0 = w + 8*pass;
    int c1 = c0 + 4;
    const float* s0 = (c0 < 16) ? (vbase + c0*NN) : (gbase + (c0-16)*NN);
    const float* s1 = (c1 < 16) ? (vbase + c1*NN) : (gbase + (c1-16)*NN);
    float acc0[4] = {0,0,0,0}, acc1[4] = {0,0,0,0};
    #pragma unroll
    for (int s8 = 0; s8 < 8; ++s8) {
      int j = l + 64*s8;
      float a0 = a4t[0][j], a1 = a4t[1][j], a2 = a4t[2][j], a3 = a4t[3][j];
      float v0 = s0[j], v1 = s1[j];
      acc0[0] = fmaf(a0, v0, acc0[0]); acc0[1] = fmaf(a1, v0, acc0[1]);
      acc0[2] = fmaf(a2, v0, acc0[2]); acc0[3] = fmaf(a3, v0, acc0[3]);
      acc1[0] = fmaf(a0, v1, acc1[0]); acc1[1] = fmaf(a1, v1, acc1[1]);
      acc1[2] = fmaf(a2, v1, acc1[2]); acc1[3] = fmaf(a3, v1, acc1[3]);
    }
    #pragma unroll
    for (int r = 0; r < 4; ++r) {
      #pragma unroll
      for (int off = 1; off < 64; off <<= 1) {
        acc0[r] += __shfl_xor(acc0[r], off);
        acc1[r] += __shfl_xor(acc1[r], off);
      }
    }
    if (l == 0) {
      #pragma unroll
      for (int r = 0; r < 4; ++r) {
        int node = b*NN + i0 + r;
        if (c0 < 16) oout[node*192 + h*16 + c0] = acc0[r];
        else         optout[node*288 + h*24 + (c0-16)] = acc0[r];
        if (c1 < 16) oout[node*192 + h*16 + c1] = acc1[r];
        else         optout[node*288 + h*24 + (c1-16)] = acc1[r];
      }
    }
  }
}

// ---------------- K4a: build feats ----------------
__global__ void k4a_feats(const float* __restrict__ oo, const float* __restrict__ opt,
                          const float* __restrict__ rot, const float* __restrict__ trans,
                          float* __restrict__ feats)
{
  int node = blockIdx.x; int t = threadIdx.x;   // 320 threads
  float* fr = feats + node*576;
  if (t < 192) {
    fr[t] = oo[node*192 + t];
  } else if (t < 288) {
    int hp = t - 192;
    const float* R = rot + node*9;
    float tx = trans[node*3+0]*0.1f, ty = trans[node*3+1]*0.1f, tz = trans[node*3+2]*0.1f;
    const float* op = opt + (node*96 + hp)*3;
    float px = op[0]-tx, py = op[1]-ty, pz = op[2]-tz;
    float lx = R[0]*px + R[3]*py + R[6]*pz;
    float ly = R[1]*px + R[4]*py + R[7]*pz;
    float lz = R[2]*px + R[5]*py + R[8]*pz;
    float d = sqrtf(lx*lx + ly*ly + lz*lz + 1e-8f);
    fr[192+hp] = lx; fr[288+hp] = ly; fr[384+hp] = lz; fr[480+hp] = d;
  }
}

// ---------------- K4b: output projection ----------------
__launch_bounds__(384)
__global__ void k4b_out(const float* __restrict__ feats, const float* __restrict__ Wout,
                        const float* __restrict__ bout, float* __restrict__ sout)
{
  const int ROWS = 8;
  int row0 = blockIdx.x * ROWS;   // grid 128
  int c = threadIdx.x;            // 384
  float acc[ROWS];
  #pragma unroll
  for (int r = 0; r < ROWS; ++r) acc[r] = 0.f;
  #pragma unroll 4
  for (int f = 0; f < 576; ++f) {
    float wv = Wout[f*384 + c];
    #pragma unroll
    for (int r = 0; r < ROWS; ++r)
      acc[r] = fmaf(feats[(row0+r)*576 + f], wv, acc[r]);   // feats uniform -> scalar
  }
  float bb = bout[c];
  #pragma unroll
  for (int r = 0; r < ROWS; ++r) sout[(row0+r)*384 + c] = acc[r] + bb;
}

// ---------------- launch ----------------
extern "C" void kernel_launch(void* const* d_in, const int* in_sizes, int n_in,
                              void* d_out, int out_size, void* d_ws, size_t ws_size,
                              hipStream_t stream)
{
  const float* s     = (const float*)d_in[0];
  const float* rot   = (const float*)d_in[1];
  const float* trans = (const float*)d_in[2];
  const float* mask  = (const float*)d_in[3];
  const float* Wq    = (const float*)d_in[4];
  const float* bq    = (const float*)d_in[5];
  const float* Wkv   = (const float*)d_in[6];
  const float* bkv   = (const float*)d_in[7];
  const float* hwts  = (const float*)d_in[8];
  const float* ln_g  = (const float*)d_in[9];
  const float* ln_b  = (const float*)d_in[10];
  const float* Wpq   = (const float*)d_in[11];
  const float* bpq   = (const float*)d_in[12];
  const float* Wpv   = (const float*)d_in[13];
  const float* bpv   = (const float*)d_in[14];
  const float* Wvl   = (const float*)d_in[15];
  const float* gbm   = (const float*)d_in[16];
  const float* gbs   = (const float*)d_in[17];
  const float* Wg    = (const float*)d_in[18];
  const float* bg    = (const float*)d_in[19];
  const float* W1    = (const float*)d_in[20];
  const float* b1    = (const float*)d_in[21];
  const float* W2    = (const float*)d_in[22];
  const float* b2    = (const float*)d_in[23];
  const float* Wkvp  = (const float*)d_in[24];
  const float* bkvp  = (const float*)d_in[25];
  const float* Wout  = (const float*)d_in[26];
  const float* bout  = (const float*)d_in[27];

  float* ws = (float*)d_ws;
  float* act   = ws + 0;          // 1024*912
  float* Wbig  = ws + 933888;     // 384*912
  float* bias  = ws + 1284096;    // 912
  float* P2    = ws + 1285008;    // 912
  float* W1T   = ws + 1285920;    // 4096
  float* hw    = ws + 1290016;    // 16
  float* mrow  = ws + 1290032;    // 1024
  float* rstd  = ws + 1291056;    // 1024
  float* vT    = ws + 1292080;    // 196608
  float* vgT   = ws + 1488688;    // 294912
  float* apre  = ws + 1783600;    // 6291456
  float* oo    = ws + 8075056;    // 196608
  float* opt   = ws + 8271664;    // 294912
  float* feats = ws + 8566576;    // 589824  (end 9156400 floats = 36.6 MB)

  float* sout = (float*)d_out;
  float* gout = sout + BB*NN*CSZ;   // g at offset 393216

  hipLaunchKernelGGL(k0_prep, dim3(256), dim3(256), 0, stream,
                     Wq, Wkv, Wpq, Wpv, Wkvp, bq, bkv, bpq, bpv, bkvp,
                     ln_g, ln_b, W1, hwts, Wbig, bias, P2, W1T, hw);
  hipLaunchKernelGGL(k0b_stats, dim3(1024), dim3(64), 0, stream, s, mrow, rstd);
  hipLaunchKernelGGL(k1_gemm, dim3(128), dim3(256), 0, stream,
                     s, Wbig, bias, P2, mrow, rstd, act);
  hipLaunchKernelGGL(k1b_post, dim3(1920), dim3(256), 0, stream, act, rot, trans, vT, vgT);
  hipLaunchKernelGGL(k2_pair, dim3(1024), dim3(256), 0, stream,
                     act, rot, trans, mask, Wvl, gbm, gbs, Wg, bg, W1T, b1, W2, b2, hw,
                     gout, apre);
  hipLaunchKernelGGL(k3_attend, dim3(3072), dim3(256), 0, stream, apre, vT, vgT, oo, opt);
  hipLaunchKernelGGL(k4a_feats, dim3(1024), dim3(320), 0, stream, oo, opt, rot, trans, feats);
  hipLaunchKernelGGL(k4b_out, dim3(128), dim3(384), 0, stream, feats, Wout, bout, sout);
}

// Round 4
// 1111.997 us; speedup vs baseline: 1.0276x; 1.0276x over previous
//
#include <hip/hip_runtime.h>
#include <math.h>

#define BB 2
#define NN 512
#define CSZ 384
#define HH 12
#define CC 16
#define PP 8
#define PVV 8
#define KG 16
#define GG 64
#define NCOL 912
#define NODES (BB*NN)

// ---------------- K0: weight prep ----------------
__global__ void k0_prep(const float* __restrict__ Wq, const float* __restrict__ Wkv,
                        const float* __restrict__ Wpq, const float* __restrict__ Wpv,
                        const float* __restrict__ Wkvp,
                        const float* __restrict__ bq, const float* __restrict__ bkv,
                        const float* __restrict__ bpq, const float* __restrict__ bpv,
                        const float* __restrict__ bkvp,
                        const float* __restrict__ ln_g, const float* __restrict__ ln_b,
                        const float* __restrict__ W1, const float* __restrict__ hwin,
                        float* __restrict__ Wbig, float* __restrict__ biasbig,
                        float* __restrict__ P2big, float* __restrict__ W1T,
                        float* __restrict__ hw)
{
  int idx = blockIdx.x*blockDim.x + threadIdx.x;
  int stride = gridDim.x*blockDim.x;
  for (int t = idx; t < CSZ*NCOL; t += stride) {
    int f = t / NCOL, c = t % NCOL;
    float w;
    if (c < 192)      w = Wq[f*192 + c];
    else if (c < 576) w = Wkv[f*384 + (c-192)];
    else if (c < 600) w = ln_g[f]*Wpq[f*24 + (c-576)];
    else if (c < 624) w = ln_g[f]*Wpv[f*24 + (c-600)];
    else              w = Wkvp[f*288 + (c-624)];
    Wbig[t] = w;
  }
  for (int t = idx; t < 64*64; t += stride) {
    int ho = t >> 6, kk = t & 63;
    W1T[t] = W1[kk*64 + ho];
  }
  for (int c = idx; c < NCOL; c += stride) {
    float bb, p2 = 0.f;
    if (c < 192)      bb = bq[c];
    else if (c < 576) bb = bkv[c-192];
    else if (c < 624) {
      const float* W = (c < 600) ? (Wpq + (c-576)) : (Wpv + (c-600));
      float p1 = 0.f;
      for (int f = 0; f < CSZ; ++f) { p1 += ln_b[f]*W[f*24]; p2 += ln_g[f]*W[f*24]; }
      bb = ((c < 600) ? bpq[c-576] : bpv[c-600]) + p1;
    }
    else bb = bkvp[c-624];
    biasbig[c] = bb; P2big[c] = p2;
  }
  for (int h = idx; h < HH; h += stride) {
    float x = hwin[h];
    float sp = (x > 20.f) ? x : log1pf(expf(x));
    hw[h] = sp * sqrtf(1.0f/18.0f) * -0.5f;   // AFS=4, AFS*4.5=18
  }
}

// ---------------- K0b: layernorm stats ----------------
__global__ void k0b_stats(const float* __restrict__ s, float* __restrict__ mout,
                          float* __restrict__ rstdout)
{
  int node = blockIdx.x;
  int l = threadIdx.x;                 // 64 threads = 1 wave
  const float* row = s + node*CSZ;
  float sum = 0.f, sum2 = 0.f;
  for (int f = l; f < CSZ; f += 64) { float v = row[f]; sum += v; sum2 += v*v; }
  #pragma unroll
  for (int off = 1; off < 64; off <<= 1) { sum += __shfl_xor(sum, off); sum2 += __shfl_xor(sum2, off); }
  if (l == 0) {
    float m = sum / CSZ;
    float var = sum2 / CSZ - m*m;
    mout[node] = m;
    rstdout[node] = rsqrtf(var + 1e-5f);
  }
}

// ---------------- K1: fused node GEMM ----------------
__launch_bounds__(256)
__global__ void k1_gemm(const float* __restrict__ s, const float* __restrict__ Wbig,
                        const float* __restrict__ biasbig, const float* __restrict__ P2big,
                        const float* __restrict__ mrow, const float* __restrict__ rstd,
                        float* __restrict__ act)
{
  const int ROWS = 8;
  int row0 = blockIdx.x * ROWS;   // grid 128
  int t = threadIdx.x;            // 256
  float acc[4][ROWS];
  #pragma unroll
  for (int j = 0; j < 4; ++j)
    #pragma unroll
    for (int r = 0; r < ROWS; ++r) acc[j][r] = 0.f;

  int c3 = t + 768;
  #pragma unroll 4
  for (int f = 0; f < CSZ; ++f) {
    const float* wrow = Wbig + f*NCOL;
    float w0 = wrow[t], w1 = wrow[t+256], w2 = wrow[t+512];
    float w3 = (c3 < NCOL) ? wrow[c3] : 0.f;
    #pragma unroll
    for (int r = 0; r < ROWS; ++r) {
      float sv = s[(row0+r)*CSZ + f];     // uniform -> scalar load
      acc[0][r] = fmaf(sv, w0, acc[0][r]);
      acc[1][r] = fmaf(sv, w1, acc[1][r]);
      acc[2][r] = fmaf(sv, w2, acc[2][r]);
      acc[3][r] = fmaf(sv, w3, acc[3][r]);
    }
  }
  #pragma unroll
  for (int j = 0; j < 4; ++j) {
    int c = t + j*256;
    if (c < NCOL) {
      float bb = biasbig[c], p2v = P2big[c];
      bool lncol = (c >= 576 && c < 624);
      #pragma unroll
      for (int r = 0; r < ROWS; ++r) {
        int node = row0 + r;
        float v;
        if (lncol) { float rs = rstd[node]; v = acc[j][r]*rs + bb - mrow[node]*rs*p2v; }
        else       v = acc[j][r] + bb;
        act[node*NCOL + c] = v;
      }
    }
  }
}

// ---------------- K1b: v transpose + vg compute ----------------
__global__ void k1b_post(const float* __restrict__ act, const float* __restrict__ rot,
                         const float* __restrict__ trans,
                         float* __restrict__ vT, float* __restrict__ vgT)
{
  int idx = blockIdx.x*blockDim.x + threadIdx.x;
  const int NT1 = BB*HH*CC*NN;       // 196608
  const int NT2 = BB*HH*PVV*3*NN;    // 294912
  if (idx < NT1) {
    int n = idx & (NN-1); int rest = idx >> 9;
    int c = rest & 15; rest >>= 4;
    int h = rest % HH; int b = rest / HH;
    int node = b*NN + n;
    vT[idx] = act[node*NCOL + 192 + h*32 + 16 + c];
  } else if (idx < NT1 + NT2) {
    int j = idx - NT1;
    int n = j & (NN-1); int rest = j >> 9;
    int p3 = rest % 24; rest /= 24;
    int h = rest % HH; int b = rest / HH;
    int node = b*NN + n;
    int p = p3 / 3, x = p3 % 3;
    int hp = h*PVV + p;
    const float* kp = act + node*NCOL + 624 + hp*3;
    const float* R = rot + node*9;
    vgT[j] = R[x*3+0]*kp[0] + R[x*3+1]*kp[1] + R[x*3+2]*kp[2] + trans[node*3+x]*0.1f;
  }
}

// ---------------- K2: fused pair kernel (r0 structure, fixed) ----------------
// grid 2048 = (bi, jj); 256 threads, ONE j per thread (NJ=1 -> live set ~150).
// Fix 1 (spills): __launch_bounds__(256,2) grants up to 256 VGPR; r0's VGPR=64
//   allocation scratch-spilled accg[64] (315MB excess WRITE_SIZE).
// Fix 2 (weight stall): Wg/W1T rows fetched via VMEM float4 loads (opaque-VGPR
//   address defeats uniform->scalar promotion). Same-address lanes coalesce to
//   one L2 request; ~32 outstanding b128s hide the ~200cy L2 latency — unlike
//   the serialized s_load stream (r0/r1) or the LDS broadcast pipe (r2).
// Fix 3: gauss exp inline (gv[16] array freed; each value used once at NJ=1).
__launch_bounds__(256, 2)
__global__ void k2_pair(const float* __restrict__ act, const float* __restrict__ rot,
                        const float* __restrict__ trans, const float* __restrict__ mask,
                        const float* __restrict__ Wvl, const float* __restrict__ gm_in,
                        const float* __restrict__ gs_in,
                        const float* __restrict__ Wg, const float* __restrict__ bg,
                        const float* __restrict__ W1T, const float* __restrict__ b1,
                        const float* __restrict__ W2, const float* __restrict__ b2,
                        const float* __restrict__ hw,
                        float* __restrict__ gout, float* __restrict__ apre)
{
  __shared__ float s_qvec[PP*3];
  __shared__ float s_gm[KG], s_gis[KG];
  __shared__ float s_hw[HH];

  int blk = blockIdx.x;           // grid 2048: (bi, jj)
  int bi = blk >> 1;
  int jj = blk & 1;
  int b = bi >> 9, i = bi & (NN-1);
  int t = threadIdx.x;
  const float* acti = act + (size_t)bi*NCOL;

  // opaque zero: forces weight loads onto the VMEM (vector) path
  int zz; asm volatile("v_mov_b32 %0, 0" : "=v"(zz));

  if (t < 24) {
    int o = t / 3, c = t % 3;
    float sum = 0.f;
    #pragma unroll
    for (int p = 0; p < PP; ++p) sum += Wvl[o*16 + 8 + p] * acti[576 + p*3 + c];
    s_qvec[t] = sum;
  } else if (t >= 32 && t < 48) {
    int k = t - 32; s_gm[k] = gm_in[k]; s_gis[k] = 1.f / gs_in[k];
  } else if (t >= 64 && t < 76) {
    s_hw[t-64] = hw[t-64];
  }
  __syncthreads();

  // block-uniform (scalar) data
  const float* Ri = rot + (size_t)bi*9;
  float ri[9];
  #pragma unroll
  for (int q = 0; q < 9; ++q) ri[q] = Ri[q];
  float ti0 = trans[bi*3], ti1 = trans[bi*3+1], ti2 = trans[bi*3+2];
  float mi = mask[bi];

  int j = t + jj*256;
  int jnode = b*NN + j;
  const float* actj = act + (size_t)jnode*NCOL;

  const float* Rj = rot + (size_t)jnode*9;
  float rj[9];
  #pragma unroll
  for (int q = 0; q < 9; ++q) rj[q] = Rj[q];
  float tj0 = trans[jnode*3], tj1 = trans[jnode*3+1], tj2 = trans[jnode*3+2];

  float Rr[9];
  #pragma unroll
  for (int x = 0; x < 3; ++x)
    #pragma unroll
    for (int z = 0; z < 3; ++z)
      Rr[x*3+z] = ri[x]*rj[z] + ri[3+x]*rj[3+z] + ri[6+x]*rj[6+z];

  float d0 = tj0-ti0, d1 = tj1-ti1, d2 = tj2-ti2;
  float tr[3];
  #pragma unroll
  for (int x = 0; x < 3; ++x) tr[x] = ri[x]*d0 + ri[3+x]*d1 + ri[6+x]*d2;

  float vpl[24];
  {
    const float4* v4 = (const float4*)(actj + 600);
    #pragma unroll
    for (int q = 0; q < 6; ++q) {
      float4 x4 = v4[q];
      vpl[q*4+0] = x4.x; vpl[q*4+1] = x4.y; vpl[q*4+2] = x4.z; vpl[q*4+3] = x4.w;
    }
  }
  // v_loc in place
  #pragma unroll
  for (int p = 0; p < PP; ++p) {
    float x0 = vpl[p*3], x1 = vpl[p*3+1], x2 = vpl[p*3+2];
    float l0 = fmaf(Rr[0], x0, fmaf(Rr[1], x1, fmaf(Rr[2], x2, tr[0])));
    float l1 = fmaf(Rr[3], x0, fmaf(Rr[4], x1, fmaf(Rr[5], x2, tr[1])));
    float l2 = fmaf(Rr[6], x0, fmaf(Rr[7], x1, fmaf(Rr[8], x2, tr[2])));
    vpl[p*3] = l0; vpl[p*3+1] = l1; vpl[p*3+2] = l2;
  }
  float vlen[8];
  #pragma unroll
  for (int o = 0; o < 8; ++o) {
    float vx = vpl[o*3+0] + s_qvec[o*3+0];
    float vy = vpl[o*3+1] + s_qvec[o*3+1];
    float vz = vpl[o*3+2] + s_qvec[o*3+2];
    #pragma unroll
    for (int p = 0; p < PP; ++p) {
      float w = Wvl[o*16+p];          // uniform -> scalar (256B, sL1-resident)
      vx = fmaf(w, vpl[p*3+0], vx);
      vy = fmaf(w, vpl[p*3+1], vy);
      vz = fmaf(w, vpl[p*3+2], vz);
    }
    vlen[o] = sqrtf(vx*vx + vy*vy + vz*vz + 1e-8f);
  }

  // ---- g = gauss @ Wg + bg (VMEM weight stream, exp inline) ----
  float accg[64];
  #pragma unroll
  for (int q = 0; q < 64; ++q) accg[q] = bg[q];
  #pragma unroll 1
  for (int o = 0; o < 8; ++o) {
    float vlo = vlen[o];
    const float* wbase = Wg + o*KG*64 + zz;   // VGPR base -> VMEM loads
    #pragma unroll 2
    for (int k = 0; k < KG; ++k) {
      float tt = (vlo - s_gm[k]) * s_gis[k];
      float gk = __expf(-0.5f * tt * tt);
      const float4* wr4 = (const float4*)(wbase + k*64);
      #pragma unroll
      for (int q = 0; q < 16; ++q) {
        float4 w4 = wr4[q];
        accg[4*q+0] = fmaf(gk, w4.x, accg[4*q+0]);
        accg[4*q+1] = fmaf(gk, w4.y, accg[4*q+1]);
        accg[4*q+2] = fmaf(gk, w4.z, accg[4*q+2]);
        accg[4*q+3] = fmaf(gk, w4.w, accg[4*q+3]);
      }
    }
  }

  // write g (output 1)
  {
    float4* gp4 = (float4*)(gout + ((size_t)bi*NN + j)*64);
    #pragma unroll
    for (int q = 0; q < 16; ++q)
      gp4[q] = make_float4(accg[4*q], accg[4*q+1], accg[4*q+2], accg[4*q+3]);
  }

  // ---- vfn = relu(g@W1+b1)@W2 + b2 (VMEM W1T stream) ----
  float vf[12];
  #pragma unroll
  for (int hh = 0; hh < 12; ++hh) vf[hh] = b2[hh];
  #pragma unroll 2
  for (int ho = 0; ho < 64; ++ho) {
    const float4* w1r = (const float4*)(W1T + ho*64 + zz);   // VMEM
    float h0 = b1[ho], h1 = 0.f, h2 = 0.f, h3 = 0.f;
    #pragma unroll
    for (int q = 0; q < 4; ++q) {
      float4 wa = w1r[q];
      float4 wb = w1r[q+4];
      float4 wc = w1r[q+8];
      float4 wd = w1r[q+12];
      h0 = fmaf(accg[4*q+0],  wa.x, h0); h0 = fmaf(accg[4*q+1],  wa.y, h0);
      h0 = fmaf(accg[4*q+2],  wa.z, h0); h0 = fmaf(accg[4*q+3],  wa.w, h0);
      h1 = fmaf(accg[16+4*q+0], wb.x, h1); h1 = fmaf(accg[16+4*q+1], wb.y, h1);
      h1 = fmaf(accg[16+4*q+2], wb.z, h1); h1 = fmaf(accg[16+4*q+3], wb.w, h1);
      h2 = fmaf(accg[32+4*q+0], wc.x, h2); h2 = fmaf(accg[32+4*q+1], wc.y, h2);
      h2 = fmaf(accg[32+4*q+2], wc.z, h2); h2 = fmaf(accg[32+4*q+3], wc.w, h2);
      h3 = fmaf(accg[48+4*q+0], wd.x, h3); h3 = fmaf(accg[48+4*q+1], wd.y, h3);
      h3 = fmaf(accg[48+4*q+2], wd.z, h3); h3 = fmaf(accg[48+4*q+3], wd.w, h3);
    }
    float hs = fmaxf((h0+h1) + (h2+h3), 0.f);
    const float* w2r = W2 + ho*12;     // uniform -> scalar (3KB, sL1-resident)
    #pragma unroll
    for (int hh = 0; hh < 12; ++hh) vf[hh] = fmaf(hs, w2r[hh], vf[hh]);
  }

  // ---- qk ----
  float qk[12];
  #pragma unroll
  for (int h = 0; h < 12; ++h) {
    const float4* k4 = (const float4*)(actj + 192 + h*32);
    float a = 0.f;
    #pragma unroll
    for (int q = 0; q < 4; ++q) {
      float4 kv = k4[q];
      const float* qp = acti + h*16 + q*4;   // uniform -> scalar
      a = fmaf(qp[0], kv.x, a); a = fmaf(qp[1], kv.y, a);
      a = fmaf(qp[2], kv.z, a); a = fmaf(qp[3], kv.w, a);
    }
    qk[h] = a;
  }

  float pd = 0.01f * (d0*d0 + d1*d1 + d2*d2);
  float mj = mask[jnode];
  float mterm = 100000.f * (mi*mj - 1.f);
  #pragma unroll
  for (int h = 0; h < 12; ++h) {
    float v = qk[h]*0.125f + vf[h]*0.5f + pd*s_hw[h] + mterm;
    apre[(((size_t)b*HH + h)*NN + i)*NN + j] = v;
  }
}

// ---------------- K3: softmax + attend ----------------
__launch_bounds__(256)
__global__ void k3_attend(const float* __restrict__ apre, const float* __restrict__ vT,
                          const float* __restrict__ vgT,
                          float* __restrict__ oout, float* __restrict__ optout)
{
  __shared__ float a4t[4][NN];     // transposed: conflict-free b32 reads
  int blk = blockIdx.x;            // B*H*(N/4)
  int ic = blk & 127; int rest = blk >> 7;
  int h = rest % HH; int b = rest / HH;
  int i0 = ic * 4;
  int t = threadIdx.x; int w = t >> 6; int l = t & 63;

  { // phase 1: wave w -> row i0+w
    int i = i0 + w;
    const float* row = apre + (((size_t)b*HH + h)*NN + i)*NN;
    float vals[8];
    float m = -1e30f;
    #pragma unroll
    for (int s8 = 0; s8 < 8; ++s8) { vals[s8] = row[l + 64*s8]; m = fmaxf(m, vals[s8]); }
    #pragma unroll
    for (int off = 1; off < 64; off <<= 1) m = fmaxf(m, __shfl_xor(m, off));
    float sum = 0.f;
    #pragma unroll
    for (int s8 = 0; s8 < 8; ++s8) { vals[s8] = __expf(vals[s8] - m); sum += vals[s8]; }
    #pragma unroll
    for (int off = 1; off < 64; off <<= 1) sum += __shfl_xor(sum, off);
    float inv = 1.f / sum;
    #pragma unroll
    for (int s8 = 0; s8 < 8; ++s8) a4t[w][l + 64*s8] = vals[s8] * inv;
  }
  __syncthreads();

  const float* vbase = vT + ((size_t)(b*HH + h)*CC)*NN;
  const float* gbase = vgT + ((size_t)(b*HH + h)*24)*NN;
  #pragma unroll 1
  for (int pass = 0; pass < 5; ++pass) {
    int c0 = w + 8*pass;
    int c1 = c0 + 4;
    const float* s0 = (c0 < 16) ? (vbase + c0*NN) : (gbase + (c0-16)*NN);
    const float* s1 = (c1 < 16) ? (vbase + c1*NN) : (gbase + (c1-16)*NN);
    float acc0[4] = {0,0,0,0}, acc1[4] = {0,0,0,0};
    #pragma unroll
    for (int s8 = 0; s8 < 8; ++s8) {
      int j = l + 64*s8;
      float a0 = a4t[0][j], a1 = a4t[1][j], a2 = a4t[2][j], a3 = a4t[3][j];
      float v0 = s0[j], v1 = s1[j];
      acc0[0] = fmaf(a0, v0, acc0[0]); acc0[1] = fmaf(a1, v0, acc0[1]);
      acc0[2] = fmaf(a2, v0, acc0[2]); acc0[3] = fmaf(a3, v0, acc0[3]);
      acc1[0] = fmaf(a0, v1, acc1[0]); acc1[1] = fmaf(a1, v1, acc1[1]);
      acc1[2] = fmaf(a2, v1, acc1[2]); acc1[3] = fmaf(a3, v1, acc1[3]);
    }
    #pragma unroll
    for (int r = 0; r < 4; ++r) {
      #pragma unroll
      for (int off = 1; off < 64; off <<= 1) {
        acc0[r] += __shfl_xor(acc0[r], off);
        acc1[r] += __shfl_xor(acc1[r], off);
      }
    }
    if (l == 0) {
      #pragma unroll
      for (int r = 0; r < 4; ++r) {
        int node = b*NN + i0 + r;
        if (c0 < 16) oout[node*192 + h*16 + c0] = acc0[r];
        else         optout[node*288 + h*24 + (c0-16)] = acc0[r];
        if (c1 < 16) oout[node*192 + h*16 + c1] = acc1[r];
        else         optout[node*288 + h*24 + (c1-16)] = acc1[r];
      }
    }
  }
}

// ---------------- K4a: build feats ----------------
__global__ void k4a_feats(const float* __restrict__ oo, const float* __restrict__ opt,
                          const float* __restrict__ rot, const float* __restrict__ trans,
                          float* __restrict__ feats)
{
  int node = blockIdx.x; int t = threadIdx.x;   // 320 threads
  float* fr = feats + node*576;
  if (t < 192) {
    fr[t] = oo[node*192 + t];
  } else if (t < 288) {
    int hp = t - 192;
    const float* R = rot + node*9;
    float tx = trans[node*3+0]*0.1f, ty = trans[node*3+1]*0.1f, tz = trans[node*3+2]*0.1f;
    const float* op = opt + (node*96 + hp)*3;
    float px = op[0]-tx, py = op[1]-ty, pz = op[2]-tz;
    float lx = R[0]*px + R[3]*py + R[6]*pz;
    float ly = R[1]*px + R[4]*py + R[7]*pz;
    float lz = R[2]*px + R[5]*py + R[8]*pz;
    float d = sqrtf(lx*lx + ly*ly + lz*lz + 1e-8f);
    fr[192+hp] = lx; fr[288+hp] = ly; fr[384+hp] = lz; fr[480+hp] = d;
  }
}

// ---------------- K4b: output projection ----------------
__launch_bounds__(384)
__global__ void k4b_out(const float* __restrict__ feats, const float* __restrict__ Wout,
                        const float* __restrict__ bout, float* __restrict__ sout)
{
  const int ROWS = 8;
  int row0 = blockIdx.x * ROWS;   // grid 128
  int c = threadIdx.x;            // 384
  float acc[ROWS];
  #pragma unroll
  for (int r = 0; r < ROWS; ++r) acc[r] = 0.f;
  #pragma unroll 4
  for (int f = 0; f < 576; ++f) {
    float wv = Wout[f*384 + c];
    #pragma unroll
    for (int r = 0; r < ROWS; ++r)
      acc[r] = fmaf(feats[(row0+r)*576 + f], wv, acc[r]);   // feats uniform -> scalar
  }
  float bb = bout[c];
  #pragma unroll
  for (int r = 0; r < ROWS; ++r) sout[(row0+r)*384 + c] = acc[r] + bb;
}

// ---------------- launch ----------------
extern "C" void kernel_launch(void* const* d_in, const int* in_sizes, int n_in,
                              void* d_out, int out_size, void* d_ws, size_t ws_size,
                              hipStream_t stream)
{
  const float* s     = (const float*)d_in[0];
  const float* rot   = (const float*)d_in[1];
  const float* trans = (const float*)d_in[2];
  const float* mask  = (const float*)d_in[3];
  const float* Wq    = (const float*)d_in[4];
  const float* bq    = (const float*)d_in[5];
  const float* Wkv   = (const float*)d_in[6];
  const float* bkv   = (const float*)d_in[7];
  const float* hwts  = (const float*)d_in[8];
  const float* ln_g  = (const float*)d_in[9];
  const float* ln_b  = (const float*)d_in[10];
  const float* Wpq   = (const float*)d_in[11];
  const float* bpq   = (const float*)d_in[12];
  const float* Wpv   = (const float*)d_in[13];
  const float* bpv   = (const float*)d_in[14];
  const float* Wvl   = (const float*)d_in[15];
  const float* gbm   = (const float*)d_in[16];
  const float* gbs   = (const float*)d_in[17];
  const float* Wg    = (const float*)d_in[18];
  const float* bg    = (const float*)d_in[19];
  const float* W1    = (const float*)d_in[20];
  const float* b1    = (const float*)d_in[21];
  const float* W2    = (const float*)d_in[22];
  const float* b2    = (const float*)d_in[23];
  const float* Wkvp  = (const float*)d_in[24];
  const float* bkvp  = (const float*)d_in[25];
  const float* Wout  = (const float*)d_in[26];
  const float* bout  = (const float*)d_in[27];

  float* ws = (float*)d_ws;
  float* act   = ws + 0;          // 1024*912
  float* Wbig  = ws + 933888;     // 384*912
  float* bias  = ws + 1284096;    // 912
  float* P2    = ws + 1285008;    // 912
  float* W1T   = ws + 1285920;    // 4096
  float* hw    = ws + 1290016;    // 16
  float* mrow  = ws + 1290032;    // 1024
  float* rstd  = ws + 1291056;    // 1024
  float* vT    = ws + 1292080;    // 196608
  float* vgT   = ws + 1488688;    // 294912
  float* apre  = ws + 1783600;    // 6291456
  float* oo    = ws + 8075056;    // 196608
  float* opt   = ws + 8271664;    // 294912
  float* feats = ws + 8566576;    // 589824  (end 9156400 floats = 36.6 MB)

  float* sout = (float*)d_out;
  float* gout = sout + BB*NN*CSZ;   // g at offset 393216

  hipLaunchKernelGGL(k0_prep, dim3(256), dim3(256), 0, stream,
                     Wq, Wkv, Wpq, Wpv, Wkvp, bq, bkv, bpq, bpv, bkvp,
                     ln_g, ln_b, W1, hwts, Wbig, bias, P2, W1T, hw);
  hipLaunchKernelGGL(k0b_stats, dim3(1024), dim3(64), 0, stream, s, mrow, rstd);
  hipLaunchKernelGGL(k1_gemm, dim3(128), dim3(256), 0, stream,
                     s, Wbig, bias, P2, mrow, rstd, act);
  hipLaunchKernelGGL(k1b_post, dim3(1920), dim3(256), 0, stream, act, rot, trans, vT, vgT);
  hipLaunchKernelGGL(k2_pair, dim3(2048), dim3(256), 0, stream,
                     act, rot, trans, mask, Wvl, gbm, gbs, Wg, bg, W1T, b1, W2, b2, hw,
                     gout, apre);
  hipLaunchKernelGGL(k3_attend, dim3(3072), dim3(256), 0, stream, apre, vT, vgT, oo, opt);
  hipLaunchKernelGGL(k4a_feats, dim3(1024), dim3(320), 0, stream, oo, opt, rot, trans, feats);
  hipLaunchKernelGGL(k4b_out, dim3(128), dim3(384), 0, stream, feats, Wout, bout, sout);
}

// Round 5
// 648.832 us; speedup vs baseline: 1.7611x; 1.7138x over previous
//
#include <hip/hip_runtime.h>
#include <math.h>

#define BB 2
#define NN 512
#define CSZ 384
#define HH 12
#define CC 16
#define PP 8
#define PVV 8
#define KG 16
#define GG 64
#define NCOL 912
#define NODES (BB*NN)

// ---------------- K0: weight prep ----------------
__global__ void k0_prep(const float* __restrict__ Wq, const float* __restrict__ Wkv,
                        const float* __restrict__ Wpq, const float* __restrict__ Wpv,
                        const float* __restrict__ Wkvp,
                        const float* __restrict__ bq, const float* __restrict__ bkv,
                        const float* __restrict__ bpq, const float* __restrict__ bpv,
                        const float* __restrict__ bkvp,
                        const float* __restrict__ ln_g, const float* __restrict__ ln_b,
                        const float* __restrict__ W1, const float* __restrict__ hwin,
                        float* __restrict__ Wbig, float* __restrict__ biasbig,
                        float* __restrict__ P2big, float* __restrict__ W1T,
                        float* __restrict__ hw)
{
  int idx = blockIdx.x*blockDim.x + threadIdx.x;
  int stride = gridDim.x*blockDim.x;
  for (int t = idx; t < CSZ*NCOL; t += stride) {
    int f = t / NCOL, c = t % NCOL;
    float w;
    if (c < 192)      w = Wq[f*192 + c];
    else if (c < 576) w = Wkv[f*384 + (c-192)];
    else if (c < 600) w = ln_g[f]*Wpq[f*24 + (c-576)];
    else if (c < 624) w = ln_g[f]*Wpv[f*24 + (c-600)];
    else              w = Wkvp[f*288 + (c-624)];
    Wbig[t] = w;
  }
  for (int t = idx; t < 64*64; t += stride) {
    int ho = t >> 6, kk = t & 63;
    W1T[t] = W1[kk*64 + ho];
  }
  for (int c = idx; c < NCOL; c += stride) {
    float bb, p2 = 0.f;
    if (c < 192)      bb = bq[c];
    else if (c < 576) bb = bkv[c-192];
    else if (c < 624) {
      const float* W = (c < 600) ? (Wpq + (c-576)) : (Wpv + (c-600));
      float p1 = 0.f;
      for (int f = 0; f < CSZ; ++f) { p1 += ln_b[f]*W[f*24]; p2 += ln_g[f]*W[f*24]; }
      bb = ((c < 600) ? bpq[c-576] : bpv[c-600]) + p1;
    }
    else bb = bkvp[c-624];
    biasbig[c] = bb; P2big[c] = p2;
  }
  for (int h = idx; h < HH; h += stride) {
    float x = hwin[h];
    float sp = (x > 20.f) ? x : log1pf(expf(x));
    hw[h] = sp * sqrtf(1.0f/18.0f) * -0.5f;   // AFS=4, AFS*4.5=18
  }
}

// ---------------- K0b: layernorm stats ----------------
__global__ void k0b_stats(const float* __restrict__ s, float* __restrict__ mout,
                          float* __restrict__ rstdout)
{
  int node = blockIdx.x;
  int l = threadIdx.x;                 // 64 threads = 1 wave
  const float* row = s + node*CSZ;
  float sum = 0.f, sum2 = 0.f;
  for (int f = l; f < CSZ; f += 64) { float v = row[f]; sum += v; sum2 += v*v; }
  #pragma unroll
  for (int off = 1; off < 64; off <<= 1) { sum += __shfl_xor(sum, off); sum2 += __shfl_xor(sum2, off); }
  if (l == 0) {
    float m = sum / CSZ;
    float var = sum2 / CSZ - m*m;
    mout[node] = m;
    rstdout[node] = rsqrtf(var + 1e-5f);
  }
}

// ---------------- K1: fused node GEMM ----------------
__launch_bounds__(256)
__global__ void k1_gemm(const float* __restrict__ s, const float* __restrict__ Wbig,
                        const float* __restrict__ biasbig, const float* __restrict__ P2big,
                        const float* __restrict__ mrow, const float* __restrict__ rstd,
                        float* __restrict__ act)
{
  const int ROWS = 8;
  int row0 = blockIdx.x * ROWS;   // grid 128
  int t = threadIdx.x;            // 256
  float acc[4][ROWS];
  #pragma unroll
  for (int j = 0; j < 4; ++j)
    #pragma unroll
    for (int r = 0; r < ROWS; ++r) acc[j][r] = 0.f;

  int c3 = t + 768;
  #pragma unroll 4
  for (int f = 0; f < CSZ; ++f) {
    const float* wrow = Wbig + f*NCOL;
    float w0 = wrow[t], w1 = wrow[t+256], w2 = wrow[t+512];
    float w3 = (c3 < NCOL) ? wrow[c3] : 0.f;
    #pragma unroll
    for (int r = 0; r < ROWS; ++r) {
      float sv = s[(row0+r)*CSZ + f];     // uniform -> scalar load
      acc[0][r] = fmaf(sv, w0, acc[0][r]);
      acc[1][r] = fmaf(sv, w1, acc[1][r]);
      acc[2][r] = fmaf(sv, w2, acc[2][r]);
      acc[3][r] = fmaf(sv, w3, acc[3][r]);
    }
  }
  #pragma unroll
  for (int j = 0; j < 4; ++j) {
    int c = t + j*256;
    if (c < NCOL) {
      float bb = biasbig[c], p2v = P2big[c];
      bool lncol = (c >= 576 && c < 624);
      #pragma unroll
      for (int r = 0; r < ROWS; ++r) {
        int node = row0 + r;
        float v;
        if (lncol) { float rs = rstd[node]; v = acc[j][r]*rs + bb - mrow[node]*rs*p2v; }
        else       v = acc[j][r] + bb;
        act[node*NCOL + c] = v;
      }
    }
  }
}

// ---------------- K1b: v transpose + vg compute ----------------
__global__ void k1b_post(const float* __restrict__ act, const float* __restrict__ rot,
                         const float* __restrict__ trans,
                         float* __restrict__ vT, float* __restrict__ vgT)
{
  int idx = blockIdx.x*blockDim.x + threadIdx.x;
  const int NT1 = BB*HH*CC*NN;       // 196608
  const int NT2 = BB*HH*PVV*3*NN;    // 294912
  if (idx < NT1) {
    int n = idx & (NN-1); int rest = idx >> 9;
    int c = rest & 15; rest >>= 4;
    int h = rest % HH; int b = rest / HH;
    int node = b*NN + n;
    vT[idx] = act[node*NCOL + 192 + h*32 + 16 + c];
  } else if (idx < NT1 + NT2) {
    int j = idx - NT1;
    int n = j & (NN-1); int rest = j >> 9;
    int p3 = rest % 24; rest /= 24;
    int h = rest % HH; int b = rest / HH;
    int node = b*NN + n;
    int p = p3 / 3, x = p3 % 3;
    int hp = h*PVV + p;
    const float* kp = act + node*NCOL + 624 + hp*3;
    const float* R = rot + node*9;
    vgT[j] = R[x*3+0]*kp[0] + R[x*3+1]*kp[1] + R[x*3+2]*kp[2] + trans[node*3+x]*0.1f;
  }
}

// ---------------- K2 helper: geometry + vlen for one j ----------------
__device__ __forceinline__ void k2_vlen(const float* __restrict__ act,
                                        const float* __restrict__ rot,
                                        const float* __restrict__ trans,
                                        const float* __restrict__ Wvl,
                                        const float* s_qvec,
                                        const float ri[9], float ti0, float ti1, float ti2,
                                        int jnode, float vlen[8], float& pd)
{
  const float* actj = act + (size_t)jnode*NCOL;
  float rj[9];
  #pragma unroll
  for (int q = 0; q < 9; ++q) rj[q] = rot[(size_t)jnode*9 + q];
  float tj0 = trans[jnode*3], tj1 = trans[jnode*3+1], tj2 = trans[jnode*3+2];

  float Rr[9];
  #pragma unroll
  for (int x = 0; x < 3; ++x)
    #pragma unroll
    for (int z = 0; z < 3; ++z)
      Rr[x*3+z] = ri[x]*rj[z] + ri[3+x]*rj[3+z] + ri[6+x]*rj[6+z];

  float d0 = tj0-ti0, d1 = tj1-ti1, d2 = tj2-ti2;
  pd = 0.01f * (d0*d0 + d1*d1 + d2*d2);
  float tr[3];
  #pragma unroll
  for (int x = 0; x < 3; ++x) tr[x] = ri[x]*d0 + ri[3+x]*d1 + ri[6+x]*d2;

  float vpl[24];
  {
    const float4* v4 = (const float4*)(actj + 600);
    #pragma unroll
    for (int q = 0; q < 6; ++q) {
      float4 x4 = v4[q];
      vpl[q*4+0] = x4.x; vpl[q*4+1] = x4.y; vpl[q*4+2] = x4.z; vpl[q*4+3] = x4.w;
    }
  }
  #pragma unroll
  for (int p = 0; p < PP; ++p) {
    float x0 = vpl[p*3], x1 = vpl[p*3+1], x2 = vpl[p*3+2];
    float l0 = fmaf(Rr[0], x0, fmaf(Rr[1], x1, fmaf(Rr[2], x2, tr[0])));
    float l1 = fmaf(Rr[3], x0, fmaf(Rr[4], x1, fmaf(Rr[5], x2, tr[1])));
    float l2 = fmaf(Rr[6], x0, fmaf(Rr[7], x1, fmaf(Rr[8], x2, tr[2])));
    vpl[p*3] = l0; vpl[p*3+1] = l1; vpl[p*3+2] = l2;
  }
  #pragma unroll
  for (int o = 0; o < 8; ++o) {
    float vx = vpl[o*3+0] + s_qvec[o*3+0];
    float vy = vpl[o*3+1] + s_qvec[o*3+1];
    float vz = vpl[o*3+2] + s_qvec[o*3+2];
    #pragma unroll
    for (int p = 0; p < PP; ++p) {
      float w = Wvl[o*16+p];          // uniform -> scalar (256B, sL1-resident)
      vx = fmaf(w, vpl[p*3+0], vx);
      vy = fmaf(w, vpl[p*3+1], vy);
      vz = fmaf(w, vpl[p*3+2], vz);
    }
    vlen[o] = sqrtf(vx*vx + vy*vy + vz*vz + 1e-8f);
  }
}

// ---------------- K2: fused pair kernel — LDS weights + NJ=2 ----------------
// grid 1024 = (b,i); 256 threads; thread t handles j=t and j=t+256.
// Delivery model (validated r2): per-CU LDS-pipe cycles = b128_count * 12cy *
// waves_per_CU. NJ=1 => 3072 b128/wave * 32 waves/CU = 492us (r2 measured 444).
// NJ=2 halves waves/CU => ~246us LDS floor; VALU ~73us/CU. Registers: ~215 live
// (acc0+acc1=128 + inflight + misc); __launch_bounds__(256,1) grants up to 512
// VGPR so the accumulators stay in TRUE VGPRs (r3: default budget -> scratch
// 450MB; r4: (256,2) -> AGPR-parking, 3x VALU via accvgpr moves).
__launch_bounds__(256, 1)
__global__ void k2_pair(const float* __restrict__ act, const float* __restrict__ rot,
                        const float* __restrict__ trans, const float* __restrict__ mask,
                        const float* __restrict__ Wvl, const float* __restrict__ gm_in,
                        const float* __restrict__ gs_in,
                        const float* __restrict__ Wg, const float* __restrict__ bg,
                        const float* __restrict__ W1T, const float* __restrict__ b1,
                        const float* __restrict__ W2, const float* __restrict__ b2,
                        const float* __restrict__ hw,
                        float* __restrict__ gout, float* __restrict__ apre)
{
  __shared__ __align__(16) float s_wg[128*64];    // 32 KB
  __shared__ __align__(16) float s_w1t[64*64];    // 16 KB
  __shared__ float s_qvec[PP*3];
  __shared__ float s_gm[KG], s_gis[KG];
  __shared__ float s_hw[HH];

  int bi = blockIdx.x;              // b*512 + i
  int b = bi >> 9, i = bi & (NN-1);
  int t = threadIdx.x;              // 256
  const float* acti = act + (size_t)bi*NCOL;

  // ---- stage weights to LDS (coalesced float4) ----
  {
    const float4* wg4 = (const float4*)Wg;
    float4* d4 = (float4*)s_wg;
    #pragma unroll
    for (int q = 0; q < 8; ++q) d4[t + 256*q] = wg4[t + 256*q];     // 2048 float4
    const float4* w14 = (const float4*)W1T;
    float4* e4 = (float4*)s_w1t;
    #pragma unroll
    for (int q = 0; q < 4; ++q) e4[t + 256*q] = w14[t + 256*q];     // 1024 float4
  }
  if (t < 24) {
    int o = t / 3, c = t % 3;
    float sum = 0.f;
    #pragma unroll
    for (int p = 0; p < PP; ++p) sum += Wvl[o*16 + 8 + p] * acti[576 + p*3 + c];
    s_qvec[t] = sum;
  } else if (t >= 32 && t < 48) {
    int k = t - 32; s_gm[k] = gm_in[k]; s_gis[k] = 1.f / gs_in[k];
  } else if (t >= 64 && t < 76) {
    s_hw[t-64] = hw[t-64];
  }
  __syncthreads();

  // block-uniform (scalar) data
  const float* Ri = rot + (size_t)bi*9;
  float ri[9];
  #pragma unroll
  for (int q = 0; q < 9; ++q) ri[q] = Ri[q];
  float ti0 = trans[bi*3], ti1 = trans[bi*3+1], ti2 = trans[bi*3+2];
  float mi = mask[bi];

  int j0 = t, j1 = t + 256;
  int jn0 = b*NN + j0, jn1 = b*NN + j1;

  float vlen0[8], vlen1[8];
  float pd0, pd1;
  k2_vlen(act, rot, trans, Wvl, s_qvec, ri, ti0, ti1, ti2, jn0, vlen0, pd0);
  k2_vlen(act, rot, trans, Wvl, s_qvec, ri, ti0, ti1, ti2, jn1, vlen1, pd1);

  // ---- g = gauss @ Wg + bg (LDS weight broadcast; one fetch -> 128 FMAs) ----
  float acc0[64], acc1[64];
  #pragma unroll
  for (int q = 0; q < 64; ++q) { float bb = bg[q]; acc0[q] = bb; acc1[q] = bb; }

  #pragma unroll 1
  for (int o = 0; o < 8; ++o) {
    float vlo0 = vlen0[o], vlo1 = vlen1[o];
    const float* wbase = s_wg + o*KG*64;
    #pragma unroll 1
    for (int k = 0; k < KG; ++k) {
      float t0 = (vlo0 - s_gm[k]) * s_gis[k];
      float t1 = (vlo1 - s_gm[k]) * s_gis[k];
      float gk0 = __expf(-0.5f * t0 * t0);
      float gk1 = __expf(-0.5f * t1 * t1);
      const float4* wr4 = (const float4*)(wbase + k*64);
      #pragma unroll
      for (int q = 0; q < 16; ++q) {
        float4 w4 = wr4[q];
        acc0[4*q+0] = fmaf(gk0, w4.x, acc0[4*q+0]);
        acc0[4*q+1] = fmaf(gk0, w4.y, acc0[4*q+1]);
        acc0[4*q+2] = fmaf(gk0, w4.z, acc0[4*q+2]);
        acc0[4*q+3] = fmaf(gk0, w4.w, acc0[4*q+3]);
        acc1[4*q+0] = fmaf(gk1, w4.x, acc1[4*q+0]);
        acc1[4*q+1] = fmaf(gk1, w4.y, acc1[4*q+1]);
        acc1[4*q+2] = fmaf(gk1, w4.z, acc1[4*q+2]);
        acc1[4*q+3] = fmaf(gk1, w4.w, acc1[4*q+3]);
      }
    }
  }

  // write g (output 1)
  {
    float4* g0 = (float4*)(gout + ((size_t)bi*NN + j0)*64);
    float4* g1 = (float4*)(gout + ((size_t)bi*NN + j1)*64);
    #pragma unroll
    for (int q = 0; q < 16; ++q) {
      g0[q] = make_float4(acc0[4*q], acc0[4*q+1], acc0[4*q+2], acc0[4*q+3]);
      g1[q] = make_float4(acc1[4*q], acc1[4*q+1], acc1[4*q+2], acc1[4*q+3]);
    }
  }

  // ---- vfn = relu(g@W1+b1)@W2 + b2 (LDS W1T broadcast, NJ=2) ----
  float vf0[12], vf1[12];
  #pragma unroll
  for (int hh = 0; hh < 12; ++hh) { float bb = b2[hh]; vf0[hh] = bb; vf1[hh] = bb; }
  #pragma unroll 1
  for (int ho = 0; ho < 64; ++ho) {
    const float4* w1r = (const float4*)(s_w1t + ho*64);
    float bb1 = b1[ho];
    float a0 = bb1, b0 = 0.f, a1 = bb1, b1v = 0.f;
    #pragma unroll
    for (int q = 0; q < 8; ++q) {
      float4 wa = w1r[q];
      float4 wb = w1r[q+8];
      a0 = fmaf(acc0[4*q+0],  wa.x, a0); a0 = fmaf(acc0[4*q+1],  wa.y, a0);
      a0 = fmaf(acc0[4*q+2],  wa.z, a0); a0 = fmaf(acc0[4*q+3],  wa.w, a0);
      b0 = fmaf(acc0[32+4*q+0], wb.x, b0); b0 = fmaf(acc0[32+4*q+1], wb.y, b0);
      b0 = fmaf(acc0[32+4*q+2], wb.z, b0); b0 = fmaf(acc0[32+4*q+3], wb.w, b0);
      a1 = fmaf(acc1[4*q+0],  wa.x, a1); a1 = fmaf(acc1[4*q+1],  wa.y, a1);
      a1 = fmaf(acc1[4*q+2],  wa.z, a1); a1 = fmaf(acc1[4*q+3],  wa.w, a1);
      b1v = fmaf(acc1[32+4*q+0], wb.x, b1v); b1v = fmaf(acc1[32+4*q+1], wb.y, b1v);
      b1v = fmaf(acc1[32+4*q+2], wb.z, b1v); b1v = fmaf(acc1[32+4*q+3], wb.w, b1v);
    }
    float hs0 = fmaxf(a0 + b0, 0.f);
    float hs1 = fmaxf(a1 + b1v, 0.f);
    const float* w2r = W2 + ho*12;     // uniform -> scalar (3KB, sL1-resident)
    #pragma unroll
    for (int hh = 0; hh < 12; ++hh) {
      float wv = w2r[hh];
      vf0[hh] = fmaf(hs0, wv, vf0[hh]);
      vf1[hh] = fmaf(hs1, wv, vf1[hh]);
    }
  }

  // ---- qk + combine + write, per j ----
  const float* actj0 = act + (size_t)jn0*NCOL;
  const float* actj1 = act + (size_t)jn1*NCOL;
  float mj0 = mask[jn0], mj1 = mask[jn1];
  float mt0 = 100000.f * (mi*mj0 - 1.f);
  float mt1 = 100000.f * (mi*mj1 - 1.f);
  #pragma unroll
  for (int h = 0; h < 12; ++h) {
    const float4* k40 = (const float4*)(actj0 + 192 + h*32);
    const float4* k41 = (const float4*)(actj1 + 192 + h*32);
    float q0 = 0.f, q1 = 0.f;
    #pragma unroll
    for (int q = 0; q < 4; ++q) {
      float4 kv0 = k40[q];
      float4 kv1 = k41[q];
      const float* qp = acti + h*16 + q*4;   // uniform -> scalar
      q0 = fmaf(qp[0], kv0.x, q0); q0 = fmaf(qp[1], kv0.y, q0);
      q0 = fmaf(qp[2], kv0.z, q0); q0 = fmaf(qp[3], kv0.w, q0);
      q1 = fmaf(qp[0], kv1.x, q1); q1 = fmaf(qp[1], kv1.y, q1);
      q1 = fmaf(qp[2], kv1.z, q1); q1 = fmaf(qp[3], kv1.w, q1);
    }
    float* arow = apre + (((size_t)b*HH + h)*NN + i)*NN;
    arow[j0] = q0*0.125f + vf0[h]*0.5f + pd0*s_hw[h] + mt0;
    arow[j1] = q1*0.125f + vf1[h]*0.5f + pd1*s_hw[h] + mt1;
  }
}

// ---------------- K3: softmax + attend ----------------
__launch_bounds__(256)
__global__ void k3_attend(const float* __restrict__ apre, const float* __restrict__ vT,
                          const float* __restrict__ vgT,
                          float* __restrict__ oout, float* __restrict__ optout)
{
  __shared__ float a4t[4][NN];     // transposed: conflict-free b32 reads
  int blk = blockIdx.x;            // B*H*(N/4)
  int ic = blk & 127; int rest = blk >> 7;
  int h = rest % HH; int b = rest / HH;
  int i0 = ic * 4;
  int t = threadIdx.x; int w = t >> 6; int l = t & 63;

  { // phase 1: wave w -> row i0+w
    int i = i0 + w;
    const float* row = apre + (((size_t)b*HH + h)*NN + i)*NN;
    float vals[8];
    float m = -1e30f;
    #pragma unroll
    for (int s8 = 0; s8 < 8; ++s8) { vals[s8] = row[l + 64*s8]; m = fmaxf(m, vals[s8]); }
    #pragma unroll
    for (int off = 1; off < 64; off <<= 1) m = fmaxf(m, __shfl_xor(m, off));
    float sum = 0.f;
    #pragma unroll
    for (int s8 = 0; s8 < 8; ++s8) { vals[s8] = __expf(vals[s8] - m); sum += vals[s8]; }
    #pragma unroll
    for (int off = 1; off < 64; off <<= 1) sum += __shfl_xor(sum, off);
    float inv = 1.f / sum;
    #pragma unroll
    for (int s8 = 0; s8 < 8; ++s8) a4t[w][l + 64*s8] = vals[s8] * inv;
  }
  __syncthreads();

  const float* vbase = vT + ((size_t)(b*HH + h)*CC)*NN;
  const float* gbase = vgT + ((size_t)(b*HH + h)*24)*NN;
  #pragma unroll 1
  for (int pass = 0; pass < 5; ++pass) {
    int c0 = w + 8*pass;
    int c1 = c0 + 4;
    const float* s0 = (c0 < 16) ? (vbase + c0*NN) : (gbase + (c0-16)*NN);
    const float* s1 = (c1 < 16) ? (vbase + c1*NN) : (gbase + (c1-16)*NN);
    float acc0[4] = {0,0,0,0}, acc1[4] = {0,0,0,0};
    #pragma unroll
    for (int s8 = 0; s8 < 8; ++s8) {
      int j = l + 64*s8;
      float a0 = a4t[0][j], a1 = a4t[1][j], a2 = a4t[2][j], a3 = a4t[3][j];
      float v0 = s0[j], v1 = s1[j];
      acc0[0] = fmaf(a0, v0, acc0[0]); acc0[1] = fmaf(a1, v0, acc0[1]);
      acc0[2] = fmaf(a2, v0, acc0[2]); acc0[3] = fmaf(a3, v0, acc0[3]);
      acc1[0] = fmaf(a0, v1, acc1[0]); acc1[1] = fmaf(a1, v1, acc1[1]);
      acc1[2] = fmaf(a2, v1, acc1[2]); acc1[3] = fmaf(a3, v1, acc1[3]);
    }
    #pragma unroll
    for (int r = 0; r < 4; ++r) {
      #pragma unroll
      for (int off = 1; off < 64; off <<= 1) {
        acc0[r] += __shfl_xor(acc0[r], off);
        acc1[r] += __shfl_xor(acc1[r], off);
      }
    }
    if (l == 0) {
      #pragma unroll
      for (int r = 0; r < 4; ++r) {
        int node = b*NN + i0 + r;
        if (c0 < 16) oout[node*192 + h*16 + c0] = acc0[r];
        else         optout[node*288 + h*24 + (c0-16)] = acc0[r];
        if (c1 < 16) oout[node*192 + h*16 + c1] = acc1[r];
        else         optout[node*288 + h*24 + (c1-16)] = acc1[r];
      }
    }
  }
}

// ---------------- K4a: build feats ----------------
__global__ void k4a_feats(const float* __restrict__ oo, const float* __restrict__ opt,
                          const float* __restrict__ rot, const float* __restrict__ trans,
                          float* __restrict__ feats)
{
  int node = blockIdx.x; int t = threadIdx.x;   // 320 threads
  float* fr = feats + node*576;
  if (t < 192) {
    fr[t] = oo[node*192 + t];
  } else if (t < 288) {
    int hp = t - 192;
    const float* R = rot + node*9;
    float tx = trans[node*3+0]*0.1f, ty = trans[node*3+1]*0.1f, tz = trans[node*3+2]*0.1f;
    const float* op = opt + (node*96 + hp)*3;
    float px = op[0]-tx, py = op[1]-ty, pz = op[2]-tz;
    float lx = R[0]*px + R[3]*py + R[6]*pz;
    float ly = R[1]*px + R[4]*py + R[7]*pz;
    float lz = R[2]*px + R[5]*py + R[8]*pz;
    float d = sqrtf(lx*lx + ly*ly + lz*lz + 1e-8f);
    fr[192+hp] = lx; fr[288+hp] = ly; fr[384+hp] = lz; fr[480+hp] = d;
  }
}

// ---------------- K4b: output projection ----------------
__launch_bounds__(384)
__global__ void k4b_out(const float* __restrict__ feats, const float* __restrict__ Wout,
                        const float* __restrict__ bout, float* __restrict__ sout)
{
  const int ROWS = 8;
  int row0 = blockIdx.x * ROWS;   // grid 128
  int c = threadIdx.x;            // 384
  float acc[ROWS];
  #pragma unroll
  for (int r = 0; r < ROWS; ++r) acc[r] = 0.f;
  #pragma unroll 4
  for (int f = 0; f < 576; ++f) {
    float wv = Wout[f*384 + c];
    #pragma unroll
    for (int r = 0; r < ROWS; ++r)
      acc[r] = fmaf(feats[(row0+r)*576 + f], wv, acc[r]);   // feats uniform -> scalar
  }
  float bb = bout[c];
  #pragma unroll
  for (int r = 0; r < ROWS; ++r) sout[(row0+r)*384 + c] = acc[r] + bb;
}

// ---------------- launch ----------------
extern "C" void kernel_launch(void* const* d_in, const int* in_sizes, int n_in,
                              void* d_out, int out_size, void* d_ws, size_t ws_size,
                              hipStream_t stream)
{
  const float* s     = (const float*)d_in[0];
  const float* rot   = (const float*)d_in[1];
  const float* trans = (const float*)d_in[2];
  const float* mask  = (const float*)d_in[3];
  const float* Wq    = (const float*)d_in[4];
  const float* bq    = (const float*)d_in[5];
  const float* Wkv   = (const float*)d_in[6];
  const float* bkv   = (const float*)d_in[7];
  const float* hwts  = (const float*)d_in[8];
  const float* ln_g  = (const float*)d_in[9];
  const float* ln_b  = (const float*)d_in[10];
  const float* Wpq   = (const float*)d_in[11];
  const float* bpq   = (const float*)d_in[12];
  const float* Wpv   = (const float*)d_in[13];
  const float* bpv   = (const float*)d_in[14];
  const float* Wvl   = (const float*)d_in[15];
  const float* gbm   = (const float*)d_in[16];
  const float* gbs   = (const float*)d_in[17];
  const float* Wg    = (const float*)d_in[18];
  const float* bg    = (const float*)d_in[19];
  const float* W1    = (const float*)d_in[20];
  const float* b1    = (const float*)d_in[21];
  const float* W2    = (const float*)d_in[22];
  const float* b2    = (const float*)d_in[23];
  const float* Wkvp  = (const float*)d_in[24];
  const float* bkvp  = (const float*)d_in[25];
  const float* Wout  = (const float*)d_in[26];
  const float* bout  = (const float*)d_in[27];

  float* ws = (float*)d_ws;
  float* act   = ws + 0;          // 1024*912
  float* Wbig  = ws + 933888;     // 384*912
  float* bias  = ws + 1284096;    // 912
  float* P2    = ws + 1285008;    // 912
  float* W1T   = ws + 1285920;    // 4096
  float* hw    = ws + 1290016;    // 16
  float* mrow  = ws + 1290032;    // 1024
  float* rstd  = ws + 1291056;    // 1024
  float* vT    = ws + 1292080;    // 196608
  float* vgT   = ws + 1488688;    // 294912
  float* apre  = ws + 1783600;    // 6291456
  float* oo    = ws + 8075056;    // 196608
  float* opt   = ws + 8271664;    // 294912
  float* feats = ws + 8566576;    // 589824  (end 9156400 floats = 36.6 MB)

  float* sout = (float*)d_out;
  float* gout = sout + BB*NN*CSZ;   // g at offset 393216

  hipLaunchKernelGGL(k0_prep, dim3(256), dim3(256), 0, stream,
                     Wq, Wkv, Wpq, Wpv, Wkvp, bq, bkv, bpq, bpv, bkvp,
                     ln_g, ln_b, W1, hwts, Wbig, bias, P2, W1T, hw);
  hipLaunchKernelGGL(k0b_stats, dim3(1024), dim3(64), 0, stream, s, mrow, rstd);
  hipLaunchKernelGGL(k1_gemm, dim3(128), dim3(256), 0, stream,
                     s, Wbig, bias, P2, mrow, rstd, act);
  hipLaunchKernelGGL(k1b_post, dim3(1920), dim3(256), 0, stream, act, rot, trans, vT, vgT);
  hipLaunchKernelGGL(k2_pair, dim3(1024), dim3(256), 0, stream,
                     act, rot, trans, mask, Wvl, gbm, gbs, Wg, bg, W1T, b1, W2, b2, hw,
                     gout, apre);
  hipLaunchKernelGGL(k3_attend, dim3(3072), dim3(256), 0, stream, apre, vT, vgT, oo, opt);
  hipLaunchKernelGGL(k4a_feats, dim3(1024), dim3(320), 0, stream, oo, opt, rot, trans, feats);
  hipLaunchKernelGGL(k4b_out, dim3(128), dim3(384), 0, stream, feats, Wout, bout, sout);
}